// Round 6
// baseline (94.991 us; speedup 1.0000x reference)
//
#include <hip/hip_runtime.h>
#include <hip/hip_bf16.h>

typedef unsigned int uint32;
typedef __attribute__((ext_vector_type(8))) short bf16x8;
typedef __attribute__((ext_vector_type(4))) float f32x4;
typedef __attribute__((ext_vector_type(2))) float f32x2;

#define MFMA(A, B, C) __builtin_amdgcn_mfma_f32_16x16x32_bf16(A, B, C, 0, 0, 0)

union FragU { uint32 u[4]; bf16x8 v; };
union BF8  { __hip_bfloat162 h2[4]; bf16x8 v; };
union F4   { f32x4 v4; f32x2 v2[2]; };

#if __has_builtin(__builtin_elementwise_fma)
#define PK_FMA(a, b, c) __builtin_elementwise_fma(a, b, c)
#define PK_MAX(a, b)    __builtin_elementwise_max(a, b)
#else
__device__ __forceinline__ f32x2 PK_FMA(f32x2 a, f32x2 b, f32x2 c) {
    f32x2 r; r[0] = fmaf(a[0], b[0], c[0]); r[1] = fmaf(a[1], b[1], c[1]); return r;
}
__device__ __forceinline__ f32x2 PK_MAX(f32x2 a, f32x2 b) {
    f32x2 r; r[0] = fmaxf(a[0], b[0]); r[1] = fmaxf(a[1], b[1]); return r;
}
#endif

// 3-pass split (phase-1 z only): hi=trunc top16, lo=bf16(x-hi)
__device__ __forceinline__ void split8(f32x4 a, f32x4 b, bf16x8& hi, bf16x8& lo) {
    float e[8] = {a[0], a[1], a[2], a[3], b[0], b[1], b[2], b[3]};
    FragU H, L;
    #pragma unroll
    for (int q = 0; q < 4; ++q) {
        uint32 u0 = __float_as_uint(e[2*q]);
        uint32 u1 = __float_as_uint(e[2*q + 1]);
        uint32 h0 = u0 & 0xFFFF0000u;
        uint32 h1 = u1 & 0xFFFF0000u;
        float l0 = e[2*q]     - __uint_as_float(h0);
        float l1 = e[2*q + 1] - __uint_as_float(h1);
        H.u[q] = (h0 >> 16) | h1;
        L.u[q] = (__float_as_uint(l0) >> 16) | (__float_as_uint(l1) & 0xFFFF0000u);
    }
    hi = H.v; lo = L.v;
}

// ---- pre-kernel: split |Wp| and W2 into RNE hi/lo bf16 pairs in d_ws ----
__global__ __launch_bounds__(256) void split_weights(
    const float* __restrict__ Wp, const float* __restrict__ W2,
    __hip_bfloat16* __restrict__ wp_hi, __hip_bfloat16* __restrict__ wp_lo,
    __hip_bfloat16* __restrict__ w2_hi, __hip_bfloat16* __restrict__ w2_lo)
{
    const int i = blockIdx.x * 256 + threadIdx.x;
    if (i < 128 * 64) {
        float x = fabsf(Wp[i]);
        __hip_bfloat16 h = __float2bfloat16(x);          // RNE
        wp_hi[i] = h;
        wp_lo[i] = __float2bfloat16(x - __bfloat162float(h));
    }
    if (i < 128 * 1024) {
        float x = W2[i];
        __hip_bfloat16 h = __float2bfloat16(x);
        w2_hi[i] = h;
        w2_lo[i] = __float2bfloat16(x - __bfloat162float(h));
    }
}

// 256 thr = 4 waves. Block: 64 samples x 128 features; wave wv owns 32 features.
// Phase 1: Y = z @ |Wp|^T (z 3-pass split x pre-split Wp) -> LDS Y[wv][64][33].
// Phase 2: per d: layer1 packed-f32 in B-frag layout; layer2 MFMA with acc
//          pre-loaded with b2 (A 2-pass presplit x B 1-pass RNE); layer3
//          packed relu*W3 in-lane + shfl_xor(16,32).
__global__ __launch_bounds__(256) void decoder_mfma(
    const float* __restrict__ z,
    const __hip_bfloat16* __restrict__ wp_hi, const __hip_bfloat16* __restrict__ wp_lo,
    const __hip_bfloat16* __restrict__ w2_hi, const __hip_bfloat16* __restrict__ w2_lo,
    const float* __restrict__ W1, const float* __restrict__ b1,
    const float* __restrict__ b2,
    const float* __restrict__ W3, const float* __restrict__ b3,
    float* __restrict__ out)
{
    __shared__ float Y[4][64][33];   // 33.8 KB, +1 pad

    const int t    = threadIdx.x;
    const int lane = t & 63;
    const int wv   = __builtin_amdgcn_readfirstlane(t >> 6);
    const int l15  = lane & 15;
    const int lg   = lane >> 4;
    const int n0   = blockIdx.x * 64;

    // ---------------- Phase 1: Y = z @ |Wp|^T -----------------------------
    bf16x8 wh[2][2], wl[2][2];
    #pragma unroll
    for (int dt = 0; dt < 2; ++dt) {
        const int d = wv*32 + dt*16 + l15;
        #pragma unroll
        for (int kt = 0; kt < 2; ++kt) {
            const int off = d*64 + kt*32 + lg*8;
            wh[dt][kt] = *(const bf16x8*)(wp_hi + off);
            wl[dt][kt] = *(const bf16x8*)(wp_lo + off);
        }
    }
    #pragma unroll
    for (int nt = 0; nt < 4; ++nt) {
        bf16x8 zh[2], zl[2];
        #pragma unroll
        for (int kt = 0; kt < 2; ++kt) {
            const float* p = z + (size_t)(n0 + nt*16 + l15)*64 + kt*32 + lg*8;
            split8(*(const f32x4*)p, *(const f32x4*)(p + 4), zh[kt], zl[kt]);
        }
        #pragma unroll
        for (int dt = 0; dt < 2; ++dt) {
            f32x4 acc = {0.f, 0.f, 0.f, 0.f};
            #pragma unroll
            for (int kt = 0; kt < 2; ++kt) {
                acc = MFMA(zh[kt], wh[dt][kt], acc);   // hi*hi
                acc = MFMA(zl[kt], wh[dt][kt], acc);   // lo*hi
                acc = MFMA(zh[kt], wl[dt][kt], acc);   // hi*lo
            }
            #pragma unroll
            for (int r = 0; r < 4; ++r)
                Y[wv][nt*16 + lg*4 + r][dt*16 + l15] = acc[r];
        }
    }
    __syncthreads();

    // ---------------- Phase 2: per-feature tiny MLP -----------------------
    #pragma unroll 1
    for (int j = 0; j < 32; ++j) {
        const int d = wv*32 + j;                 // wave-uniform feature
        // A-frags: pre-split W2[d] rows (k2 = rt*16+l15), k = h = lg*8+i
        bf16x8 ah[2], al[2];
        #pragma unroll
        for (int rt = 0; rt < 2; ++rt) {
            const int off = d*1024 + (rt*16 + l15)*32 + lg*8;
            ah[rt] = *(const bf16x8*)(w2_hi + off);
            al[rt] = *(const bf16x8*)(w2_lo + off);
        }
        F4 w1a, w1b, b1a, b1b, b2a, b2b, w3a, w3b;
        w1a.v4 = *(const f32x4*)(W1 + d*32 + lg*8);
        w1b.v4 = *(const f32x4*)(W1 + d*32 + lg*8 + 4);
        b1a.v4 = *(const f32x4*)(b1 + d*32 + lg*8);
        b1b.v4 = *(const f32x4*)(b1 + d*32 + lg*8 + 4);
        b2a.v4 = *(const f32x4*)(b2 + d*32 + lg*4);        // rows k2 = lg*4+r
        b2b.v4 = *(const f32x4*)(b2 + d*32 + 16 + lg*4);
        w3a.v4 = *(const f32x4*)(W3 + d*32 + lg*4);
        w3b.v4 = *(const f32x4*)(W3 + d*32 + 16 + lg*4);
        const float b3v = b3[d];
        const f32x2 zero2 = {0.f, 0.f};

        #pragma unroll
        for (int ct = 0; ct < 4; ++ct) {
            // layer 1 (packed f32): lane -> sample n = ct*16+l15, h = lg*8..+7
            const float y = Y[wv][ct*16 + l15][j];
            const f32x2 y2 = {y, y};
            f32x2 h[4];
            h[0] = PK_MAX(PK_FMA(y2, w1a.v2[0], b1a.v2[0]), zero2);
            h[1] = PK_MAX(PK_FMA(y2, w1a.v2[1], b1a.v2[1]), zero2);
            h[2] = PK_MAX(PK_FMA(y2, w1b.v2[0], b1b.v2[0]), zero2);
            h[3] = PK_MAX(PK_FMA(y2, w1b.v2[1], b1b.v2[1]), zero2);
            BF8 pk;
            #pragma unroll
            for (int q = 0; q < 4; ++q)
                pk.h2[q] = __float22bfloat162_rn(make_float2(h[q][0], h[q][1]));
            // layer 2: D[k2, n] = W2[k2,:] . h1[n,:] + b2[k2]  (acc init = b2)
            f32x4 a0 = b2a.v4, a1 = b2b.v4;
            a0 = MFMA(ah[0], pk.v, a0);
            a0 = MFMA(al[0], pk.v, a0);
            a1 = MFMA(ah[1], pk.v, a1);
            a1 = MFMA(al[1], pk.v, a1);
            // layer 3 (packed): rows k2 = rt*16 + lg*4 + r live in-lane
            F4 u0, u1; u0.v4 = a0; u1.v4 = a1;
            f32x2 s2 = zero2;
            s2 = PK_FMA(PK_MAX(u0.v2[0], zero2), w3a.v2[0], s2);
            s2 = PK_FMA(PK_MAX(u0.v2[1], zero2), w3a.v2[1], s2);
            s2 = PK_FMA(PK_MAX(u1.v2[0], zero2), w3b.v2[0], s2);
            s2 = PK_FMA(PK_MAX(u1.v2[1], zero2), w3b.v2[1], s2);
            float s = s2[0] + s2[1];
            s += __shfl_xor(s, 16);      // reduce over the 4 lg groups
            s += __shfl_xor(s, 32);
            const float x = fabsf(s + b3v);
            if (lane < 16) Y[wv][ct*16 + lane][j] = x;
        }
    }
    __syncthreads();

    // ---------------- coalesced copy-out ----------------------------------
    const int cg = lane & 7;
    #pragma unroll
    for (int it = 0; it < 8; ++it) {
        const int n = it*8 + (lane >> 3);
        f32x4 v;
        #pragma unroll
        for (int c = 0; c < 4; ++c) v[c] = Y[wv][n][cg*4 + c];
        *(f32x4*)(out + (size_t)(n0 + n)*128 + wv*32 + cg*4) = v;
    }
}

extern "C" void kernel_launch(void* const* d_in, const int* in_sizes, int n_in,
                              void* d_out, int out_size, void* d_ws, size_t ws_size,
                              hipStream_t stream) {
    const float* z  = (const float*)d_in[0];
    const float* Wp = (const float*)d_in[1];
    const float* W1 = (const float*)d_in[2];
    const float* b1 = (const float*)d_in[3];
    const float* W2 = (const float*)d_in[4];
    const float* b2 = (const float*)d_in[5];
    const float* W3 = (const float*)d_in[6];
    const float* b3 = (const float*)d_in[7];
    float* out = (float*)d_out;

    __hip_bfloat16* wp_hi = (__hip_bfloat16*)d_ws;
    __hip_bfloat16* wp_lo = wp_hi + 128 * 64;
    __hip_bfloat16* w2_hi = wp_lo + 128 * 64;
    __hip_bfloat16* w2_lo = w2_hi + 128 * 1024;

    hipLaunchKernelGGL(split_weights, dim3(512), dim3(256), 0, stream,
                       Wp, W2, wp_hi, wp_lo, w2_hi, w2_lo);
    hipLaunchKernelGGL(decoder_mfma, dim3(65536 / 64), dim3(256), 0, stream,
                       z, wp_hi, wp_lo, w2_hi, w2_lo, W1, b1, b2, W3, b3, out);
}

// Round 7
// 86.032 us; speedup vs baseline: 1.1041x; 1.1041x over previous
//
#include <hip/hip_runtime.h>
#include <hip/hip_bf16.h>

typedef unsigned int uint32;
typedef __attribute__((ext_vector_type(8))) short bf16x8;
typedef __attribute__((ext_vector_type(4))) float f32x4;

#define MFMA(A, B, C) __builtin_amdgcn_mfma_f32_16x16x32_bf16(A, B, C, 0, 0, 0)

union FragU { uint32 u[4]; bf16x8 v; };
union BF8  { __hip_bfloat162 h2[4]; bf16x8 v; };

// 3-pass split (phase-1 z only): hi=trunc top16, lo=bf16(x-hi)
__device__ __forceinline__ void split8(f32x4 a, f32x4 b, bf16x8& hi, bf16x8& lo) {
    float e[8] = {a[0], a[1], a[2], a[3], b[0], b[1], b[2], b[3]};
    FragU H, L;
    #pragma unroll
    for (int q = 0; q < 4; ++q) {
        uint32 u0 = __float_as_uint(e[2*q]);
        uint32 u1 = __float_as_uint(e[2*q + 1]);
        uint32 h0 = u0 & 0xFFFF0000u;
        uint32 h1 = u1 & 0xFFFF0000u;
        float l0 = e[2*q]     - __uint_as_float(h0);
        float l1 = e[2*q + 1] - __uint_as_float(h1);
        H.u[q] = (h0 >> 16) | h1;
        L.u[q] = (__float_as_uint(l0) >> 16) | (__float_as_uint(l1) & 0xFFFF0000u);
    }
    hi = H.v; lo = L.v;
}

// ---- pre-kernel: split |Wp| and W2 into RNE hi/lo bf16 pairs in d_ws ----
__global__ __launch_bounds__(256) void split_weights(
    const float* __restrict__ Wp, const float* __restrict__ W2,
    __hip_bfloat16* __restrict__ wp_hi, __hip_bfloat16* __restrict__ wp_lo,
    __hip_bfloat16* __restrict__ w2_hi, __hip_bfloat16* __restrict__ w2_lo)
{
    const int i = blockIdx.x * 256 + threadIdx.x;
    if (i < 128 * 64) {
        float x = fabsf(Wp[i]);
        __hip_bfloat16 h = __float2bfloat16(x);          // RNE
        wp_hi[i] = h;
        wp_lo[i] = __float2bfloat16(x - __bfloat162float(h));
    }
    if (i < 128 * 1024) {
        float x = W2[i];
        __hip_bfloat16 h = __float2bfloat16(x);
        w2_hi[i] = h;
        w2_lo[i] = __float2bfloat16(x - __bfloat162float(h));
    }
}

// 256 thr = 4 waves. Block: 64 samples x 128 features; wave wv owns 32 features.
// Phase 1: Y = z @ |Wp|^T (z 3-pass split x pre-split Wp) -> LDS Y[wv][64][33].
// Phase 2 (batched for ILP): per j -> 4 y-reads | 4 layer1+packs | 8 hi-MFMA |
//          8 lo-MFMA (acc init = b2) | 4 layer3 tails. 4 independent chains.
__global__ __launch_bounds__(256, 4) void decoder_mfma(
    const float* __restrict__ z,
    const __hip_bfloat16* __restrict__ wp_hi, const __hip_bfloat16* __restrict__ wp_lo,
    const __hip_bfloat16* __restrict__ w2_hi, const __hip_bfloat16* __restrict__ w2_lo,
    const float* __restrict__ W1, const float* __restrict__ b1,
    const float* __restrict__ b2,
    const float* __restrict__ W3, const float* __restrict__ b3,
    float* __restrict__ out)
{
    __shared__ float Y[4][64][33];   // 33.8 KB, +1 pad

    const int t    = threadIdx.x;
    const int lane = t & 63;
    const int wv   = __builtin_amdgcn_readfirstlane(t >> 6);
    const int l15  = lane & 15;
    const int lg   = lane >> 4;
    const int n0   = blockIdx.x * 64;

    // ---------------- Phase 1: Y = z @ |Wp|^T -----------------------------
    bf16x8 wh[2][2], wl[2][2];
    #pragma unroll
    for (int dt = 0; dt < 2; ++dt) {
        const int d = wv*32 + dt*16 + l15;
        #pragma unroll
        for (int kt = 0; kt < 2; ++kt) {
            const int off = d*64 + kt*32 + lg*8;
            wh[dt][kt] = *(const bf16x8*)(wp_hi + off);
            wl[dt][kt] = *(const bf16x8*)(wp_lo + off);
        }
    }
    #pragma unroll
    for (int nt = 0; nt < 4; ++nt) {
        bf16x8 zh[2], zl[2];
        #pragma unroll
        for (int kt = 0; kt < 2; ++kt) {
            const float* p = z + (size_t)(n0 + nt*16 + l15)*64 + kt*32 + lg*8;
            split8(*(const f32x4*)p, *(const f32x4*)(p + 4), zh[kt], zl[kt]);
        }
        #pragma unroll
        for (int dt = 0; dt < 2; ++dt) {
            f32x4 acc = {0.f, 0.f, 0.f, 0.f};
            #pragma unroll
            for (int kt = 0; kt < 2; ++kt) {
                acc = MFMA(zh[kt], wh[dt][kt], acc);   // hi*hi
                acc = MFMA(zl[kt], wh[dt][kt], acc);   // lo*hi
                acc = MFMA(zh[kt], wl[dt][kt], acc);   // hi*lo
            }
            #pragma unroll
            for (int r = 0; r < 4; ++r)
                Y[wv][nt*16 + lg*4 + r][dt*16 + l15] = acc[r];
        }
    }
    __syncthreads();

    // ---------------- Phase 2: per-feature tiny MLP (batched) -------------
    #pragma unroll 2
    for (int j = 0; j < 32; ++j) {
        const int d = wv*32 + j;                 // wave-uniform feature
        // A-frags: pre-split W2[d] rows (k2 = rt*16+l15), k = h = lg*8+i
        bf16x8 ah[2], al[2];
        #pragma unroll
        for (int rt = 0; rt < 2; ++rt) {
            const int off = d*1024 + (rt*16 + l15)*32 + lg*8;
            ah[rt] = *(const bf16x8*)(w2_hi + off);
            al[rt] = *(const bf16x8*)(w2_lo + off);
        }
        const f32x4 w1a = *(const f32x4*)(W1 + d*32 + lg*8);
        const f32x4 w1b = *(const f32x4*)(W1 + d*32 + lg*8 + 4);
        const f32x4 b1a = *(const f32x4*)(b1 + d*32 + lg*8);
        const f32x4 b1b = *(const f32x4*)(b1 + d*32 + lg*8 + 4);
        const f32x4 b2a = *(const f32x4*)(b2 + d*32 + lg*4);        // k2 = lg*4+r
        const f32x4 b2b = *(const f32x4*)(b2 + d*32 + 16 + lg*4);
        const f32x4 w3a = *(const f32x4*)(W3 + d*32 + lg*4);
        const f32x4 w3b = *(const f32x4*)(W3 + d*32 + 16 + lg*4);
        const float b3v = b3[d];

        // ---- 4 y reads issued together (one lgkm wait) ----
        float yv[4];
        #pragma unroll
        for (int ct = 0; ct < 4; ++ct) yv[ct] = Y[wv][ct*16 + l15][j];

        // ---- 4 independent layer1 + pack chains ----
        bf16x8 pk[4];
        #pragma unroll
        for (int ct = 0; ct < 4; ++ct) {
            const float y = yv[ct];
            float h0[4], h1v[4];
            #pragma unroll
            for (int i = 0; i < 4; ++i) h0[i]  = fmaxf(fmaf(y, w1a[i], b1a[i]), 0.f);
            #pragma unroll
            for (int i = 0; i < 4; ++i) h1v[i] = fmaxf(fmaf(y, w1b[i], b1b[i]), 0.f);
            BF8 r;
            r.h2[0] = __float22bfloat162_rn(make_float2(h0[0], h0[1]));
            r.h2[1] = __float22bfloat162_rn(make_float2(h0[2], h0[3]));
            r.h2[2] = __float22bfloat162_rn(make_float2(h1v[0], h1v[1]));
            r.h2[3] = __float22bfloat162_rn(make_float2(h1v[2], h1v[3]));
            pk[ct] = r.v;
        }

        // ---- 16 MFMAs: 8 hi first, then 8 lo (dep pairs 7 apart) ----
        f32x4 A0[4], A1[4];
        #pragma unroll
        for (int ct = 0; ct < 4; ++ct) { A0[ct] = b2a; A1[ct] = b2b; }
        #pragma unroll
        for (int ct = 0; ct < 4; ++ct) {
            A0[ct] = MFMA(ah[0], pk[ct], A0[ct]);
            A1[ct] = MFMA(ah[1], pk[ct], A1[ct]);
        }
        #pragma unroll
        for (int ct = 0; ct < 4; ++ct) {
            A0[ct] = MFMA(al[0], pk[ct], A0[ct]);
            A1[ct] = MFMA(al[1], pk[ct], A1[ct]);
        }

        // ---- 4 independent layer3 tails ----
        #pragma unroll
        for (int ct = 0; ct < 4; ++ct) {
            float s = fmaxf(A0[ct][0], 0.f) * w3a[0];
            s = fmaf(fmaxf(A0[ct][1], 0.f), w3a[1], s);
            s = fmaf(fmaxf(A0[ct][2], 0.f), w3a[2], s);
            s = fmaf(fmaxf(A0[ct][3], 0.f), w3a[3], s);
            s = fmaf(fmaxf(A1[ct][0], 0.f), w3b[0], s);
            s = fmaf(fmaxf(A1[ct][1], 0.f), w3b[1], s);
            s = fmaf(fmaxf(A1[ct][2], 0.f), w3b[2], s);
            s = fmaf(fmaxf(A1[ct][3], 0.f), w3b[3], s);
            s += __shfl_xor(s, 16);      // reduce over the 4 lg groups
            s += __shfl_xor(s, 32);
            const float x = fabsf(s + b3v);
            if (lane < 16) Y[wv][ct*16 + lane][j] = x;
        }
    }
    __syncthreads();

    // ---------------- coalesced copy-out ----------------------------------
    const int cg = lane & 7;
    #pragma unroll
    for (int it = 0; it < 8; ++it) {
        const int n = it*8 + (lane >> 3);
        f32x4 v;
        #pragma unroll
        for (int c = 0; c < 4; ++c) v[c] = Y[wv][n][cg*4 + c];
        *(f32x4*)(out + (size_t)(n0 + n)*128 + wv*32 + cg*4) = v;
    }
}

extern "C" void kernel_launch(void* const* d_in, const int* in_sizes, int n_in,
                              void* d_out, int out_size, void* d_ws, size_t ws_size,
                              hipStream_t stream) {
    const float* z  = (const float*)d_in[0];
    const float* Wp = (const float*)d_in[1];
    const float* W1 = (const float*)d_in[2];
    const float* b1 = (const float*)d_in[3];
    const float* W2 = (const float*)d_in[4];
    const float* b2 = (const float*)d_in[5];
    const float* W3 = (const float*)d_in[6];
    const float* b3 = (const float*)d_in[7];
    float* out = (float*)d_out;

    __hip_bfloat16* wp_hi = (__hip_bfloat16*)d_ws;
    __hip_bfloat16* wp_lo = wp_hi + 128 * 64;
    __hip_bfloat16* w2_hi = wp_lo + 128 * 64;
    __hip_bfloat16* w2_lo = w2_hi + 128 * 1024;

    hipLaunchKernelGGL(split_weights, dim3(512), dim3(256), 0, stream,
                       Wp, W2, wp_hi, wp_lo, w2_hi, w2_lo);
    hipLaunchKernelGGL(decoder_mfma, dim3(65536 / 64), dim3(256), 0, stream,
                       z, wp_hi, wp_lo, w2_hi, w2_lo, W1, b1, b2, W3, b3, out);
}

// Round 8
// 85.680 us; speedup vs baseline: 1.1087x; 1.0041x over previous
//
#include <hip/hip_runtime.h>
#include <hip/hip_bf16.h>

typedef unsigned int uint32;
typedef __attribute__((ext_vector_type(8))) short bf16x8;
typedef __attribute__((ext_vector_type(4))) float f32x4;

#define MFMA(A, B, C) __builtin_amdgcn_mfma_f32_16x16x32_bf16(A, B, C, 0, 0, 0)

union FragU { uint32 u[4]; bf16x8 v; };

// HW packed f32->bf16 RNE convert (no builtin on gfx950; 1 instr per 2 floats).
// Result: lo -> bits[15:0], hi -> bits[31:16].
__device__ __forceinline__ uint32 cvt_pk_bf16(float lo, float hi) {
    uint32 r;
    asm("v_cvt_pk_bf16_f32 %0, %1, %2" : "=v"(r) : "v"(lo), "v"(hi));
    return r;
}

// 3-pass split (phase-1 z only): hi=trunc top16, lo=bf16(x-hi)
__device__ __forceinline__ void split8(f32x4 a, f32x4 b, bf16x8& hi, bf16x8& lo) {
    float e[8] = {a[0], a[1], a[2], a[3], b[0], b[1], b[2], b[3]};
    FragU H, L;
    #pragma unroll
    for (int q = 0; q < 4; ++q) {
        uint32 u0 = __float_as_uint(e[2*q]);
        uint32 u1 = __float_as_uint(e[2*q + 1]);
        uint32 h0 = u0 & 0xFFFF0000u;
        uint32 h1 = u1 & 0xFFFF0000u;
        float l0 = e[2*q]     - __uint_as_float(h0);
        float l1 = e[2*q + 1] - __uint_as_float(h1);
        H.u[q] = (h0 >> 16) | h1;
        L.u[q] = (__float_as_uint(l0) >> 16) | (__float_as_uint(l1) & 0xFFFF0000u);
    }
    hi = H.v; lo = L.v;
}

// ---- pre-kernel: split |Wp| and W2 into RNE hi/lo bf16 pairs in d_ws ----
__global__ __launch_bounds__(256) void split_weights(
    const float* __restrict__ Wp, const float* __restrict__ W2,
    __hip_bfloat16* __restrict__ wp_hi, __hip_bfloat16* __restrict__ wp_lo,
    __hip_bfloat16* __restrict__ w2_hi, __hip_bfloat16* __restrict__ w2_lo)
{
    const int i = blockIdx.x * 256 + threadIdx.x;
    if (i < 128 * 64) {
        float x = fabsf(Wp[i]);
        __hip_bfloat16 h = __float2bfloat16(x);          // RNE
        wp_hi[i] = h;
        wp_lo[i] = __float2bfloat16(x - __bfloat162float(h));
    }
    if (i < 128 * 1024) {
        float x = W2[i];
        __hip_bfloat16 h = __float2bfloat16(x);
        w2_hi[i] = h;
        w2_lo[i] = __float2bfloat16(x - __bfloat162float(h));
    }
}

// 256 thr = 4 waves. Block: 64 samples x 128 features; wave wv owns 32 features.
// Phase 1: Y = z @ |Wp|^T (z 3-pass split x pre-split Wp) -> LDS Y[wv][64][33].
// Phase 2 (batched, unroll-4): per j -> 4 y-reads | 4 layer1 + HW cvt_pk packs |
//          8 hi-MFMA | 8 lo-MFMA (acc init = b2) | 4 layer3 tails.
__global__ __launch_bounds__(256, 4) void decoder_mfma(
    const float* __restrict__ z,
    const __hip_bfloat16* __restrict__ wp_hi, const __hip_bfloat16* __restrict__ wp_lo,
    const __hip_bfloat16* __restrict__ w2_hi, const __hip_bfloat16* __restrict__ w2_lo,
    const float* __restrict__ W1, const float* __restrict__ b1,
    const float* __restrict__ b2,
    const float* __restrict__ W3, const float* __restrict__ b3,
    float* __restrict__ out)
{
    __shared__ float Y[4][64][33];   // 33.8 KB, +1 pad

    const int t    = threadIdx.x;
    const int lane = t & 63;
    const int wv   = __builtin_amdgcn_readfirstlane(t >> 6);
    const int l15  = lane & 15;
    const int lg   = lane >> 4;
    const int n0   = blockIdx.x * 64;

    // ---------------- Phase 1: Y = z @ |Wp|^T -----------------------------
    bf16x8 wh[2][2], wl[2][2];
    #pragma unroll
    for (int dt = 0; dt < 2; ++dt) {
        const int d = wv*32 + dt*16 + l15;
        #pragma unroll
        for (int kt = 0; kt < 2; ++kt) {
            const int off = d*64 + kt*32 + lg*8;
            wh[dt][kt] = *(const bf16x8*)(wp_hi + off);
            wl[dt][kt] = *(const bf16x8*)(wp_lo + off);
        }
    }
    #pragma unroll
    for (int nt = 0; nt < 4; ++nt) {
        bf16x8 zh[2], zl[2];
        #pragma unroll
        for (int kt = 0; kt < 2; ++kt) {
            const float* p = z + (size_t)(n0 + nt*16 + l15)*64 + kt*32 + lg*8;
            split8(*(const f32x4*)p, *(const f32x4*)(p + 4), zh[kt], zl[kt]);
        }
        #pragma unroll
        for (int dt = 0; dt < 2; ++dt) {
            f32x4 acc = {0.f, 0.f, 0.f, 0.f};
            #pragma unroll
            for (int kt = 0; kt < 2; ++kt) {
                acc = MFMA(zh[kt], wh[dt][kt], acc);   // hi*hi
                acc = MFMA(zl[kt], wh[dt][kt], acc);   // lo*hi
                acc = MFMA(zh[kt], wl[dt][kt], acc);   // hi*lo
            }
            #pragma unroll
            for (int r = 0; r < 4; ++r)
                Y[wv][nt*16 + lg*4 + r][dt*16 + l15] = acc[r];
        }
    }
    __syncthreads();

    // ---------------- Phase 2: per-feature tiny MLP (batched) -------------
    #pragma unroll 4
    for (int j = 0; j < 32; ++j) {
        const int d = wv*32 + j;                 // wave-uniform feature
        // A-frags: pre-split W2[d] rows (k2 = rt*16+l15), k = h = lg*8+i
        bf16x8 ah[2], al[2];
        #pragma unroll
        for (int rt = 0; rt < 2; ++rt) {
            const int off = d*1024 + (rt*16 + l15)*32 + lg*8;
            ah[rt] = *(const bf16x8*)(w2_hi + off);
            al[rt] = *(const bf16x8*)(w2_lo + off);
        }
        const f32x4 w1a = *(const f32x4*)(W1 + d*32 + lg*8);
        const f32x4 w1b = *(const f32x4*)(W1 + d*32 + lg*8 + 4);
        const f32x4 b1a = *(const f32x4*)(b1 + d*32 + lg*8);
        const f32x4 b1b = *(const f32x4*)(b1 + d*32 + lg*8 + 4);
        const f32x4 b2a = *(const f32x4*)(b2 + d*32 + lg*4);        // k2 = lg*4+r
        const f32x4 b2b = *(const f32x4*)(b2 + d*32 + 16 + lg*4);
        const f32x4 w3a = *(const f32x4*)(W3 + d*32 + lg*4);
        const f32x4 w3b = *(const f32x4*)(W3 + d*32 + 16 + lg*4);
        const float b3v = b3[d];

        // ---- 4 y reads issued together (one lgkm wait) ----
        float yv[4];
        #pragma unroll
        for (int ct = 0; ct < 4; ++ct) yv[ct] = Y[wv][ct*16 + l15][j];

        // ---- 4 independent layer1 + HW-pack chains ----
        bf16x8 pk[4];
        #pragma unroll
        for (int ct = 0; ct < 4; ++ct) {
            const float y = yv[ct];
            float h0[4], h1v[4];
            #pragma unroll
            for (int i = 0; i < 4; ++i) h0[i]  = fmaxf(fmaf(y, w1a[i], b1a[i]), 0.f);
            #pragma unroll
            for (int i = 0; i < 4; ++i) h1v[i] = fmaxf(fmaf(y, w1b[i], b1b[i]), 0.f);
            FragU r;
            r.u[0] = cvt_pk_bf16(h0[0], h0[1]);
            r.u[1] = cvt_pk_bf16(h0[2], h0[3]);
            r.u[2] = cvt_pk_bf16(h1v[0], h1v[1]);
            r.u[3] = cvt_pk_bf16(h1v[2], h1v[3]);
            pk[ct] = r.v;
        }

        // ---- 16 MFMAs: 8 hi first, then 8 lo (dep pairs 7 apart) ----
        f32x4 A0[4], A1[4];
        #pragma unroll
        for (int ct = 0; ct < 4; ++ct) { A0[ct] = b2a; A1[ct] = b2b; }
        #pragma unroll
        for (int ct = 0; ct < 4; ++ct) {
            A0[ct] = MFMA(ah[0], pk[ct], A0[ct]);
            A1[ct] = MFMA(ah[1], pk[ct], A1[ct]);
        }
        #pragma unroll
        for (int ct = 0; ct < 4; ++ct) {
            A0[ct] = MFMA(al[0], pk[ct], A0[ct]);
            A1[ct] = MFMA(al[1], pk[ct], A1[ct]);
        }

        // ---- 4 independent layer3 tails ----
        #pragma unroll
        for (int ct = 0; ct < 4; ++ct) {
            float s = fmaxf(A0[ct][0], 0.f) * w3a[0];
            s = fmaf(fmaxf(A0[ct][1], 0.f), w3a[1], s);
            s = fmaf(fmaxf(A0[ct][2], 0.f), w3a[2], s);
            s = fmaf(fmaxf(A0[ct][3], 0.f), w3a[3], s);
            s = fmaf(fmaxf(A1[ct][0], 0.f), w3b[0], s);
            s = fmaf(fmaxf(A1[ct][1], 0.f), w3b[1], s);
            s = fmaf(fmaxf(A1[ct][2], 0.f), w3b[2], s);
            s = fmaf(fmaxf(A1[ct][3], 0.f), w3b[3], s);
            s += __shfl_xor(s, 16);      // reduce over the 4 lg groups
            s += __shfl_xor(s, 32);
            const float x = fabsf(s + b3v);
            if (lane < 16) Y[wv][ct*16 + lane][j] = x;
        }
    }
    __syncthreads();

    // ---------------- coalesced copy-out ----------------------------------
    const int cg = lane & 7;
    #pragma unroll
    for (int it = 0; it < 8; ++it) {
        const int n = it*8 + (lane >> 3);
        f32x4 v;
        #pragma unroll
        for (int c = 0; c < 4; ++c) v[c] = Y[wv][n][cg*4 + c];
        *(f32x4*)(out + (size_t)(n0 + n)*128 + wv*32 + cg*4) = v;
    }
}

extern "C" void kernel_launch(void* const* d_in, const int* in_sizes, int n_in,
                              void* d_out, int out_size, void* d_ws, size_t ws_size,
                              hipStream_t stream) {
    const float* z  = (const float*)d_in[0];
    const float* Wp = (const float*)d_in[1];
    const float* W1 = (const float*)d_in[2];
    const float* b1 = (const float*)d_in[3];
    const float* W2 = (const float*)d_in[4];
    const float* b2 = (const float*)d_in[5];
    const float* W3 = (const float*)d_in[6];
    const float* b3 = (const float*)d_in[7];
    float* out = (float*)d_out;

    __hip_bfloat16* wp_hi = (__hip_bfloat16*)d_ws;
    __hip_bfloat16* wp_lo = wp_hi + 128 * 64;
    __hip_bfloat16* w2_hi = wp_lo + 128 * 64;
    __hip_bfloat16* w2_lo = w2_hi + 128 * 1024;

    hipLaunchKernelGGL(split_weights, dim3(512), dim3(256), 0, stream,
                       Wp, W2, wp_hi, wp_lo, w2_hi, w2_lo);
    hipLaunchKernelGGL(decoder_mfma, dim3(65536 / 64), dim3(256), 0, stream,
                       z, wp_hi, wp_lo, w2_hi, w2_lo, W1, b1, b2, W3, b3, out);
}

// Round 9
// 85.328 us; speedup vs baseline: 1.1132x; 1.0041x over previous
//
#include <hip/hip_runtime.h>
#include <hip/hip_bf16.h>

typedef unsigned int uint32;
typedef __attribute__((ext_vector_type(8))) short bf16x8;
typedef __attribute__((ext_vector_type(4))) float f32x4;

#define MFMA(A, B, C) __builtin_amdgcn_mfma_f32_16x16x32_bf16(A, B, C, 0, 0, 0)

union FragU { uint32 u[4]; bf16x8 v; };
union BF8  { __hip_bfloat162 h2[4]; bf16x8 v; };

// 3-pass split (phase-1 z only): hi=trunc top16, lo=bf16(x-hi)
__device__ __forceinline__ void split8(f32x4 a, f32x4 b, bf16x8& hi, bf16x8& lo) {
    float e[8] = {a[0], a[1], a[2], a[3], b[0], b[1], b[2], b[3]};
    FragU H, L;
    #pragma unroll
    for (int q = 0; q < 4; ++q) {
        uint32 u0 = __float_as_uint(e[2*q]);
        uint32 u1 = __float_as_uint(e[2*q + 1]);
        uint32 h0 = u0 & 0xFFFF0000u;
        uint32 h1 = u1 & 0xFFFF0000u;
        float l0 = e[2*q]     - __uint_as_float(h0);
        float l1 = e[2*q + 1] - __uint_as_float(h1);
        H.u[q] = (h0 >> 16) | h1;
        L.u[q] = (__float_as_uint(l0) >> 16) | (__float_as_uint(l1) & 0xFFFF0000u);
    }
    hi = H.v; lo = L.v;
}

// ---- pre-kernel: split |Wp| and W2 into RNE hi/lo bf16 pairs in d_ws ----
__global__ __launch_bounds__(256) void split_weights(
    const float* __restrict__ Wp, const float* __restrict__ W2,
    __hip_bfloat16* __restrict__ wp_hi, __hip_bfloat16* __restrict__ wp_lo,
    __hip_bfloat16* __restrict__ w2_hi, __hip_bfloat16* __restrict__ w2_lo)
{
    const int i = blockIdx.x * 256 + threadIdx.x;
    if (i < 128 * 64) {
        float x = fabsf(Wp[i]);
        __hip_bfloat16 h = __float2bfloat16(x);          // RNE
        wp_hi[i] = h;
        wp_lo[i] = __float2bfloat16(x - __bfloat162float(h));
    }
    if (i < 128 * 1024) {
        float x = W2[i];
        __hip_bfloat16 h = __float2bfloat16(x);
        w2_hi[i] = h;
        w2_lo[i] = __float2bfloat16(x - __bfloat162float(h));
    }
}

// 1 WAVE per block (waves were already independent): 64 samples x 32 features.
// LDS = 8.45 KB/block -> ~18 blocks/CU (vs 4 x 33.8KB before) = +50% waves/SIMD
// to hide the per-j serial chain (LDS read -> layer1 -> pack -> MFMA -> layer3
// -> shfl -> LDS write). Identical math to round 8.
__global__ __launch_bounds__(64, 4) void decoder_mfma(
    const float* __restrict__ z,
    const __hip_bfloat16* __restrict__ wp_hi, const __hip_bfloat16* __restrict__ wp_lo,
    const __hip_bfloat16* __restrict__ w2_hi, const __hip_bfloat16* __restrict__ w2_lo,
    const float* __restrict__ W1, const float* __restrict__ b1,
    const float* __restrict__ b2,
    const float* __restrict__ W3, const float* __restrict__ b3,
    float* __restrict__ out)
{
    __shared__ float Y[64][33];      // 8448 B, +1 pad: conflict-free column reads

    const int lane = threadIdx.x;    // 0..63
    const int l15  = lane & 15;
    const int lg   = lane >> 4;
    const int g    = blockIdx.x & 3;           // feature group: [32g, 32g+32)
    const int n0   = (blockIdx.x >> 2) * 64;   // sample tile

    // ---------------- Phase 1: Y = z @ |Wp|^T -----------------------------
    bf16x8 wh[2][2], wl[2][2];
    #pragma unroll
    for (int dt = 0; dt < 2; ++dt) {
        const int d = g*32 + dt*16 + l15;
        #pragma unroll
        for (int kt = 0; kt < 2; ++kt) {
            const int off = d*64 + kt*32 + lg*8;
            wh[dt][kt] = *(const bf16x8*)(wp_hi + off);
            wl[dt][kt] = *(const bf16x8*)(wp_lo + off);
        }
    }
    #pragma unroll
    for (int nt = 0; nt < 4; ++nt) {
        bf16x8 zh[2], zl[2];
        #pragma unroll
        for (int kt = 0; kt < 2; ++kt) {
            const float* p = z + (size_t)(n0 + nt*16 + l15)*64 + kt*32 + lg*8;
            split8(*(const f32x4*)p, *(const f32x4*)(p + 4), zh[kt], zl[kt]);
        }
        #pragma unroll
        for (int dt = 0; dt < 2; ++dt) {
            f32x4 acc = {0.f, 0.f, 0.f, 0.f};
            #pragma unroll
            for (int kt = 0; kt < 2; ++kt) {
                acc = MFMA(zh[kt], wh[dt][kt], acc);   // hi*hi
                acc = MFMA(zl[kt], wh[dt][kt], acc);   // lo*hi
                acc = MFMA(zh[kt], wl[dt][kt], acc);   // hi*lo
            }
            #pragma unroll
            for (int r = 0; r < 4; ++r)
                Y[nt*16 + lg*4 + r][dt*16 + l15] = acc[r];
        }
    }
    __syncthreads();

    // ---------------- Phase 2: per-feature tiny MLP (batched) -------------
    #pragma unroll 4
    for (int j = 0; j < 32; ++j) {
        const int d = g*32 + j;                  // wave-uniform feature
        // A-frags: pre-split W2[d] rows (k2 = rt*16+l15), k = h = lg*8+i
        bf16x8 ah[2], al[2];
        #pragma unroll
        for (int rt = 0; rt < 2; ++rt) {
            const int off = d*1024 + (rt*16 + l15)*32 + lg*8;
            ah[rt] = *(const bf16x8*)(w2_hi + off);
            al[rt] = *(const bf16x8*)(w2_lo + off);
        }
        const f32x4 w1a = *(const f32x4*)(W1 + d*32 + lg*8);
        const f32x4 w1b = *(const f32x4*)(W1 + d*32 + lg*8 + 4);
        const f32x4 b1a = *(const f32x4*)(b1 + d*32 + lg*8);
        const f32x4 b1b = *(const f32x4*)(b1 + d*32 + lg*8 + 4);
        const f32x4 b2a = *(const f32x4*)(b2 + d*32 + lg*4);        // k2 = lg*4+r
        const f32x4 b2b = *(const f32x4*)(b2 + d*32 + 16 + lg*4);
        const f32x4 w3a = *(const f32x4*)(W3 + d*32 + lg*4);
        const f32x4 w3b = *(const f32x4*)(W3 + d*32 + 16 + lg*4);
        const float b3v = b3[d];

        // ---- 4 y reads issued together (one lgkm wait) ----
        float yv[4];
        #pragma unroll
        for (int ct = 0; ct < 4; ++ct) yv[ct] = Y[ct*16 + l15][j];

        // ---- 4 independent layer1 + pack chains ----
        bf16x8 pk[4];
        #pragma unroll
        for (int ct = 0; ct < 4; ++ct) {
            const float y = yv[ct];
            float h0[4], h1v[4];
            #pragma unroll
            for (int i = 0; i < 4; ++i) h0[i]  = fmaxf(fmaf(y, w1a[i], b1a[i]), 0.f);
            #pragma unroll
            for (int i = 0; i < 4; ++i) h1v[i] = fmaxf(fmaf(y, w1b[i], b1b[i]), 0.f);
            BF8 r;
            r.h2[0] = __float22bfloat162_rn(make_float2(h0[0], h0[1]));
            r.h2[1] = __float22bfloat162_rn(make_float2(h0[2], h0[3]));
            r.h2[2] = __float22bfloat162_rn(make_float2(h1v[0], h1v[1]));
            r.h2[3] = __float22bfloat162_rn(make_float2(h1v[2], h1v[3]));
            pk[ct] = r.v;
        }

        // ---- 16 MFMAs: 8 hi first, then 8 lo (dep pairs far apart) ----
        f32x4 A0[4], A1[4];
        #pragma unroll
        for (int ct = 0; ct < 4; ++ct) { A0[ct] = b2a; A1[ct] = b2b; }
        #pragma unroll
        for (int ct = 0; ct < 4; ++ct) {
            A0[ct] = MFMA(ah[0], pk[ct], A0[ct]);
            A1[ct] = MFMA(ah[1], pk[ct], A1[ct]);
        }
        #pragma unroll
        for (int ct = 0; ct < 4; ++ct) {
            A0[ct] = MFMA(al[0], pk[ct], A0[ct]);
            A1[ct] = MFMA(al[1], pk[ct], A1[ct]);
        }

        // ---- 4 independent layer3 tails ----
        #pragma unroll
        for (int ct = 0; ct < 4; ++ct) {
            float s = fmaxf(A0[ct][0], 0.f) * w3a[0];
            s = fmaf(fmaxf(A0[ct][1], 0.f), w3a[1], s);
            s = fmaf(fmaxf(A0[ct][2], 0.f), w3a[2], s);
            s = fmaf(fmaxf(A0[ct][3], 0.f), w3a[3], s);
            s = fmaf(fmaxf(A1[ct][0], 0.f), w3b[0], s);
            s = fmaf(fmaxf(A1[ct][1], 0.f), w3b[1], s);
            s = fmaf(fmaxf(A1[ct][2], 0.f), w3b[2], s);
            s = fmaf(fmaxf(A1[ct][3], 0.f), w3b[3], s);
            s += __shfl_xor(s, 16);      // reduce over the 4 lg groups
            s += __shfl_xor(s, 32);
            const float x = fabsf(s + b3v);
            if (lane < 16) Y[ct*16 + lane][j] = x;
        }
    }
    __syncthreads();

    // ---------------- coalesced copy-out ----------------------------------
    const int cg = lane & 7;
    #pragma unroll
    for (int it = 0; it < 8; ++it) {
        const int n = it*8 + (lane >> 3);
        f32x4 v;
        #pragma unroll
        for (int c = 0; c < 4; ++c) v[c] = Y[n][cg*4 + c];
        *(f32x4*)(out + (size_t)(n0 + n)*128 + g*32 + cg*4) = v;
    }
}

extern "C" void kernel_launch(void* const* d_in, const int* in_sizes, int n_in,
                              void* d_out, int out_size, void* d_ws, size_t ws_size,
                              hipStream_t stream) {
    const float* z  = (const float*)d_in[0];
    const float* Wp = (const float*)d_in[1];
    const float* W1 = (const float*)d_in[2];
    const float* b1 = (const float*)d_in[3];
    const float* W2 = (const float*)d_in[4];
    const float* b2 = (const float*)d_in[5];
    const float* W3 = (const float*)d_in[6];
    const float* b3 = (const float*)d_in[7];
    float* out = (float*)d_out;

    __hip_bfloat16* wp_hi = (__hip_bfloat16*)d_ws;
    __hip_bfloat16* wp_lo = wp_hi + 128 * 64;
    __hip_bfloat16* w2_hi = wp_lo + 128 * 64;
    __hip_bfloat16* w2_lo = w2_hi + 128 * 1024;

    hipLaunchKernelGGL(split_weights, dim3(512), dim3(256), 0, stream,
                       Wp, W2, wp_hi, wp_lo, w2_hi, w2_lo);
    // 4096 one-wave blocks: bid&3 = feature group, bid>>2 = sample tile
    hipLaunchKernelGGL(decoder_mfma, dim3(4096), dim3(64), 0, stream,
                       z, wp_hi, wp_lo, w2_hi, w2_lo, W1, b1, b2, W3, b3, out);
}